// Round 1
// baseline (281.899 us; speedup 1.0000x reference)
//
#include <hip/hip_runtime.h>
#include <hip/hip_bf16.h>

// Problem constants
#define BB 32
#define SS 256
#define DD 300
#define PDD 32
#define MM 66
#define FF 398      // D + PD + M
#define HH 6
#define G4 24       // 4*H
#define AA 12

__device__ __forceinline__ float fast_rcp(float x) { return __builtin_amdgcn_rcpf(x); }
__device__ __forceinline__ float sigmoidf_(float x) { return fast_rcp(1.f + __expf(-x)); }
__device__ __forceinline__ float fast_tanh(float x) {
    // tanh(x) = 1 - 2/(exp(2x)+1); saturates correctly at +-inf via expf over/underflow
    return 1.f - 2.f * fast_rcp(__expf(2.f * x) + 1.f);
}

// -------------------------------------------------------------------------
// Kernel 1: embedding concat + input projection for both LSTM directions.
// 16 positions per block, feats staged in LDS; Wx tables stay L1-hot and are
// amortized 16x (avoids ~626MB of cache traffic the naive version would do).
// -------------------------------------------------------------------------
#define NP 16
__global__ __launch_bounds__(256) void k_embed_proj(
    const int* __restrict__ words, const int* __restrict__ pos,
    const float* __restrict__ morph, const float* __restrict__ wtab,
    const float* __restrict__ ptab,
    const float* __restrict__ Wxf, const float* __restrict__ bfv,
    const float* __restrict__ Wxb, const float* __restrict__ bbv,
    float* __restrict__ xgf, float* __restrict__ xgb)
{
    __shared__ float sf[NP][400];           // 398 padded to 400
    int t = threadIdx.x;                    // 0..255
    int p0 = blockIdx.x * NP;               // first (b*S+s) index
    int pl = t >> 4;                        // position 0..15
    int ll = t & 15;                        // loader lane 0..15
    int bs = p0 + pl;

    const float* wrow = wtab + (size_t)words[bs] * DD;
    for (int k = ll; k < DD; k += 16) sf[pl][k] = wrow[k];
    const float* prow = ptab + pos[bs] * PDD;
    sf[pl][DD + ll]      = prow[ll];
    sf[pl][DD + 16 + ll] = prow[16 + ll];
    const float* mrow = morph + (size_t)bs * MM;
    for (int k = ll; k < MM; k += 16) sf[pl][DD + PDD + k] = mrow[k];
    __syncthreads();

    // 16 positions x 48 outputs (24 fwd + 24 bwd) = 768 outputs
    for (int o = t; o < NP * 48; o += 256) {
        int p = o / 48;
        int col = o % 48;
        bool fwd = col < G4;
        int j = fwd ? col : col - G4;
        const float* Wx = fwd ? Wxf : Wxb;
        float acc = fwd ? bfv[j] : bbv[j];
        const float* fr = sf[p];
        #pragma unroll 2
        for (int k = 0; k < FF; ++k) acc = fmaf(fr[k], Wx[k * G4 + j], acc);
        (fwd ? xgf : xgb)[(size_t)(p0 + p) * G4 + j] = acc;
    }
}

// -------------------------------------------------------------------------
// Kernel 2: LSTM recurrence. One wave per (batch, direction). xg slice
// (256x24 floats = 24KB) staged in LDS; h/c replicated across lanes; gates
// computed by lanes 0..23 and broadcast via shfl. keras gate order i,f,c,o.
// -------------------------------------------------------------------------
__global__ __launch_bounds__(64) void k_lstm(
    const float* __restrict__ xgf, const float* __restrict__ xgb,
    const float* __restrict__ Whf, const float* __restrict__ Whb,
    float* __restrict__ repr)
{
    __shared__ float sxg[SS * G4];          // 24576 B
    int blk = blockIdx.x;                   // 0..63
    int dir = blk >> 5;                     // 0 = fwd, 1 = bwd
    int b   = blk & 31;
    int lane = threadIdx.x;

    const float* xg = (dir ? xgb : xgf) + (size_t)b * SS * G4;
    const float* Wh = dir ? Whb : Whf;
    for (int k = lane; k < SS * G4; k += 64) sxg[k] = xg[k];

    int j = lane % G4;                      // lanes >=24 duplicate (harmless)
    float wh[HH];
    #pragma unroll
    for (int k = 0; k < HH; ++k) wh[k] = Wh[k * G4 + j];
    float h[HH], c[HH];
    #pragma unroll
    for (int k = 0; k < HH; ++k) { h[k] = 0.f; c[k] = 0.f; }
    __syncthreads();

    for (int t = 0; t < SS; ++t) {
        int s = dir ? (SS - 1 - t) : t;
        float g = sxg[s * G4 + j];
        #pragma unroll
        for (int k = 0; k < HH; ++k) g = fmaf(h[k], wh[k], g);
        #pragma unroll
        for (int k = 0; k < HH; ++k) {
            float gi = __shfl(g, k,        64);
            float gf = __shfl(g, k + HH,   64);
            float gc = __shfl(g, k + 2*HH, 64);
            float go = __shfl(g, k + 3*HH, 64);
            float cn = sigmoidf_(gf) * c[k] + sigmoidf_(gi) * fast_tanh(gc);
            c[k] = cn;
            h[k] = sigmoidf_(go) * fast_tanh(cn);
        }
        if (lane < HH)
            repr[((size_t)b * SS + s) * (2 * HH) + dir * HH + lane] = h[lane];
    }
}

// -------------------------------------------------------------------------
// Kernel 3: ua = repr@Wu+bu ; wa = repr@Ww+bw. One thread per (b,s).
// -------------------------------------------------------------------------
__global__ __launch_bounds__(256) void k_uawa(
    const float* __restrict__ repr,
    const float* __restrict__ Wu, const float* __restrict__ bu,
    const float* __restrict__ Ww, const float* __restrict__ bw,
    float* __restrict__ ua, float* __restrict__ wa)
{
    int bs = blockIdx.x * blockDim.x + threadIdx.x;   // 0..8191
    float r[AA];
    #pragma unroll
    for (int e = 0; e < AA; ++e) r[e] = repr[(size_t)bs * AA + e];
    #pragma unroll
    for (int d = 0; d < AA; ++d) {
        float au = bu[d], aw = bw[d];
        #pragma unroll
        for (int e = 0; e < AA; ++e) {
            au = fmaf(r[e], Wu[e * AA + d], au);
            aw = fmaf(r[e], Ww[e * AA + d], aw);
        }
        ua[(size_t)bs * AA + d] = au;
        wa[(size_t)bs * AA + d] = aw;
    }
}

// -------------------------------------------------------------------------
// Kernel 4: arc scores + logsumexp + CE partials + exp table.
// Block = (b,i); thread j computes scores[b,i,j].
// -------------------------------------------------------------------------
__global__ __launch_bounds__(256) void k_score(
    const float* __restrict__ ua, const float* __restrict__ wa,
    const float* __restrict__ v, const int* __restrict__ heads,
    float* __restrict__ out, float* __restrict__ ce)
{
    int bi = blockIdx.x;            // b*S + i
    int b  = bi >> 8;
    int i  = bi & 255;
    int j  = threadIdx.x;

    __shared__ float swa[AA], sv[AA];
    if (j < AA) { swa[j] = wa[(size_t)bi * AA + j]; sv[j] = v[j]; }
    __syncthreads();

    const float* uj = ua + ((size_t)(bi & ~255) + j) * AA;
    float s = 0.f;
    #pragma unroll
    for (int d = 0; d < AA; ++d) s = fmaf(sv[d], fast_tanh(uj[d] + swa[d]), s);
    if (j == i) s = -10000.f;

    __shared__ float red[256];
    red[j] = s; __syncthreads();
    for (int off = 128; off > 0; off >>= 1) {
        if (j < off) red[j] = fmaxf(red[j], red[j + off]);
        __syncthreads();
    }
    float m = red[0]; __syncthreads();
    red[j] = __expf(s - m); __syncthreads();
    for (int off = 128; off > 0; off >>= 1) {
        if (j < off) red[j] += red[j + off];
        __syncthreads();
    }
    float lse = m + __logf(red[0]);

    if (i >= 1)
        out[1 + (((size_t)(i - 1) * BB + b) * SS + j)] = __expf(s);
    if (j == heads[bi])
        ce[bi] = (i >= 1) ? (lse - s) : 0.f;
}

// -------------------------------------------------------------------------
// Kernel 5: deterministic loss reduction: sum(ce)/B into out[0].
// -------------------------------------------------------------------------
__global__ __launch_bounds__(256) void k_loss(const float* __restrict__ ce,
                                              float* __restrict__ out)
{
    __shared__ float red[256];
    int t = threadIdx.x;
    float a = 0.f;
    for (int k = t; k < BB * SS; k += 256) a += ce[k];
    red[t] = a; __syncthreads();
    for (int off = 128; off > 0; off >>= 1) {
        if (t < off) red[t] += red[t + off];
        __syncthreads();
    }
    if (t == 0) out[0] = red[0] * (1.f / BB);
}

extern "C" void kernel_launch(void* const* d_in, const int* in_sizes, int n_in,
                              void* d_out, int out_size, void* d_ws, size_t ws_size,
                              hipStream_t stream)
{
    const int*   words = (const int*)  d_in[0];
    const int*   pos   = (const int*)  d_in[1];
    const float* morph = (const float*)d_in[2];
    const int*   heads = (const int*)  d_in[3];
    const float* wtab  = (const float*)d_in[4];
    const float* ptab  = (const float*)d_in[5];
    const float* Wxf   = (const float*)d_in[6];
    const float* Whf   = (const float*)d_in[7];
    const float* bf    = (const float*)d_in[8];
    const float* Wxb   = (const float*)d_in[9];
    const float* Whb   = (const float*)d_in[10];
    const float* bb    = (const float*)d_in[11];
    const float* Wu    = (const float*)d_in[12];
    const float* bu    = (const float*)d_in[13];
    const float* Ww    = (const float*)d_in[14];
    const float* bw    = (const float*)d_in[15];
    const float* v     = (const float*)d_in[16];
    float* out = (float*)d_out;

    // workspace layout (floats)
    float* xgf  = (float*)d_ws;                 // 8192*24
    float* xgb  = xgf  + (size_t)BB*SS*G4;      // 8192*24
    float* repr = xgb  + (size_t)BB*SS*G4;      // 8192*12
    float* ua   = repr + (size_t)BB*SS*2*HH;    // 8192*12
    float* wa   = ua   + (size_t)BB*SS*AA;      // 8192*12
    float* ce   = wa   + (size_t)BB*SS*AA;      // 8192

    k_embed_proj<<<(BB * SS) / NP, 256, 0, stream>>>(words, pos, morph, wtab, ptab,
                                                     Wxf, bf, Wxb, bb, xgf, xgb);
    k_lstm<<<BB * 2, 64, 0, stream>>>(xgf, xgb, Whf, Whb, repr);
    k_uawa<<<(BB * SS) / 256, 256, 0, stream>>>(repr, Wu, bu, Ww, bw, ua, wa);
    k_score<<<BB * SS, 256, 0, stream>>>(ua, wa, v, heads, out, ce);
    k_loss<<<1, 256, 0, stream>>>(ce, out);
}

// Round 2
// 143.300 us; speedup vs baseline: 1.9672x; 1.9672x over previous
//
#include <hip/hip_runtime.h>
#include <hip/hip_bf16.h>

// Problem constants
#define BB 32
#define SS 256
#define DD 300
#define PDD 32
#define MM 66
#define FF 398      // D + PD + M
#define HH 6
#define G4 24       // 4*H
#define AA 12

__device__ __forceinline__ float fast_rcp(float x) { return __builtin_amdgcn_rcpf(x); }
__device__ __forceinline__ float sigmoidf_(float x) { return fast_rcp(1.f + __expf(-x)); }
__device__ __forceinline__ float fast_tanh(float x) {
    // tanh(x) = 1 - 2/(exp(2x)+1); saturates correctly at +-inf via expf over/underflow
    return 1.f - 2.f * fast_rcp(__expf(2.f * x) + 1.f);
}
__device__ __forceinline__ float bcast_lane(float x, int l) {
    return __int_as_float(__builtin_amdgcn_readlane(__float_as_int(x), l));
}

// -------------------------------------------------------------------------
// Kernel 1: embedding concat + input projection for both LSTM directions.
// 16 positions per block, feats staged in LDS; Wx tables stay L1-hot and are
// amortized 16x.
// -------------------------------------------------------------------------
#define NP 16
__global__ __launch_bounds__(256) void k_embed_proj(
    const int* __restrict__ words, const int* __restrict__ pos,
    const float* __restrict__ morph, const float* __restrict__ wtab,
    const float* __restrict__ ptab,
    const float* __restrict__ Wxf, const float* __restrict__ bfv,
    const float* __restrict__ Wxb, const float* __restrict__ bbv,
    float* __restrict__ xgf, float* __restrict__ xgb)
{
    __shared__ float sf[NP][400];           // 398 padded to 400
    int t = threadIdx.x;                    // 0..255
    int p0 = blockIdx.x * NP;               // first (b*S+s) index
    int pl = t >> 4;                        // position 0..15
    int ll = t & 15;                        // loader lane 0..15
    int bs = p0 + pl;

    const float* wrow = wtab + (size_t)words[bs] * DD;
    for (int k = ll; k < DD; k += 16) sf[pl][k] = wrow[k];
    const float* prow = ptab + pos[bs] * PDD;
    sf[pl][DD + ll]      = prow[ll];
    sf[pl][DD + 16 + ll] = prow[16 + ll];
    const float* mrow = morph + (size_t)bs * MM;
    for (int k = ll; k < MM; k += 16) sf[pl][DD + PDD + k] = mrow[k];
    __syncthreads();

    // 16 positions x 48 outputs (24 fwd + 24 bwd) = 768 outputs
    for (int o = t; o < NP * 48; o += 256) {
        int p = o / 48;
        int col = o % 48;
        bool fwd = col < G4;
        int j = fwd ? col : col - G4;
        const float* Wx = fwd ? Wxf : Wxb;
        float acc = fwd ? bfv[j] : bbv[j];
        const float* fr = sf[p];
        #pragma unroll 2
        for (int k = 0; k < FF; ++k) acc = fmaf(fr[k], Wx[k * G4 + j], acc);
        (fwd ? xgf : xgb)[(size_t)(p0 + p) * G4 + j] = acc;
    }
}

// -------------------------------------------------------------------------
// Kernel 2: LSTM recurrence, shuffle-free critical path.
// One wave per (batch, direction). Lane k owns cell k (lanes >=6 compute
// redundant copies, k = lane%6). Per step: 4 gates for own cell via
// SGPR-broadcast h (v_readlane, no LDS round-trip), local transcendental
// chain, store h, broadcast. xg staged in LDS, next-step reads prefetched
// one iteration ahead so ds_read latency hides under compute.
// -------------------------------------------------------------------------
__global__ __launch_bounds__(64) void k_lstm(
    const float* __restrict__ xgf, const float* __restrict__ xgb,
    const float* __restrict__ Whf, const float* __restrict__ Whb,
    float* __restrict__ repr)
{
    __shared__ float sxg[SS * G4];          // 24576 B
    int blk = blockIdx.x;                   // 0..63
    int dir = blk >> 5;                     // 0 = fwd, 1 = bwd
    int b   = blk & 31;
    int lane = threadIdx.x;

    const float* xg = (dir ? xgb : xgf) + (size_t)b * SS * G4;
    const float* Wh = dir ? Whb : Whf;

    // stage xg -> LDS (vectorized, 24 float4 per lane)
    {
        const float4* src = (const float4*)xg;
        float4* dst = (float4*)sxg;
        for (int u = 0; u < (SS * G4 / 4) / 64; ++u)
            dst[lane + u * 64] = src[lane + u * 64];
    }

    int k = lane % HH;                      // cell id
    // per-lane recurrent weights: whq[m] = Wh[m][q*6+k]
    float wh0[HH], wh1[HH], wh2[HH], wh3[HH];
    #pragma unroll
    for (int m = 0; m < HH; ++m) {
        wh0[m] = Wh[m * G4 + 0 * HH + k];
        wh1[m] = Wh[m * G4 + 1 * HH + k];
        wh2[m] = Wh[m * G4 + 2 * HH + k];
        wh3[m] = Wh[m * G4 + 3 * HH + k];
    }
    float sh[HH];
    #pragma unroll
    for (int m = 0; m < HH; ++m) sh[m] = 0.f;
    float c = 0.f;
    __syncthreads();

    float* outp = repr + (size_t)b * SS * (2 * HH) + dir * HH + k;

    int s = dir ? (SS - 1) : 0;
    const float* xr = sxg + s * G4 + k;
    float gi = xr[0], gf = xr[HH], gc = xr[2 * HH], go = xr[3 * HH];

    for (int t = 0; t < SS; ++t) {
        // prefetch next step's gate inputs (independent of recurrence)
        int tn = (t + 1 < SS) ? t + 1 : t;
        int sn = dir ? (SS - 1 - tn) : tn;
        const float* xn = sxg + sn * G4 + k;
        float ni = xn[0], nf = xn[HH], nc = xn[2 * HH], no = xn[3 * HH];

        #pragma unroll
        for (int m = 0; m < HH; ++m) {
            gi = fmaf(sh[m], wh0[m], gi);
            gf = fmaf(sh[m], wh1[m], gf);
            gc = fmaf(sh[m], wh2[m], gc);
            go = fmaf(sh[m], wh3[m], go);
        }
        c = sigmoidf_(gf) * c + sigmoidf_(gi) * fast_tanh(gc);
        float h = sigmoidf_(go) * fast_tanh(c);
        if (lane < HH) outp[(size_t)s * (2 * HH)] = h;
        // SGPR broadcast of new h (lanes 0..5 are canonical)
        #pragma unroll
        for (int m = 0; m < HH; ++m) sh[m] = bcast_lane(h, m);

        gi = ni; gf = nf; gc = nc; go = no;
        s = sn;
    }
}

// -------------------------------------------------------------------------
// Kernel 3: ua = repr@Wu+bu ; wa = repr@Ww+bw. One thread per (b,s).
// -------------------------------------------------------------------------
__global__ __launch_bounds__(256) void k_uawa(
    const float* __restrict__ repr,
    const float* __restrict__ Wu, const float* __restrict__ bu,
    const float* __restrict__ Ww, const float* __restrict__ bw,
    float* __restrict__ ua, float* __restrict__ wa)
{
    int bs = blockIdx.x * blockDim.x + threadIdx.x;   // 0..8191
    float r[AA];
    #pragma unroll
    for (int e = 0; e < AA; ++e) r[e] = repr[(size_t)bs * AA + e];
    #pragma unroll
    for (int d = 0; d < AA; ++d) {
        float au = bu[d], aw = bw[d];
        #pragma unroll
        for (int e = 0; e < AA; ++e) {
            au = fmaf(r[e], Wu[e * AA + d], au);
            aw = fmaf(r[e], Ww[e * AA + d], aw);
        }
        ua[(size_t)bs * AA + d] = au;
        wa[(size_t)bs * AA + d] = aw;
    }
}

// -------------------------------------------------------------------------
// Kernel 4: arc scores + sum-exp + CE partials + exp table.
// Scores are bounded (|s| <= sum|v| ~ 4), so no max-shift needed; the masked
// -10000 underflows exp() to exactly 0, matching numpy. One wave-level
// shfl_xor sum + one cross-wave LDS combine replaces the two tree passes.
// -------------------------------------------------------------------------
__global__ __launch_bounds__(256) void k_score(
    const float* __restrict__ ua, const float* __restrict__ wa,
    const float* __restrict__ v, const int* __restrict__ heads,
    float* __restrict__ out, float* __restrict__ ce)
{
    int bi = blockIdx.x;            // b*S + i
    int i  = bi & 255;
    int j  = threadIdx.x;

    __shared__ float swa[AA], sv[AA];
    if (j < AA) { swa[j] = wa[(size_t)bi * AA + j]; sv[j] = v[j]; }
    __syncthreads();

    const float* uj = ua + ((size_t)(bi & ~255) + j) * AA;
    float s = 0.f;
    #pragma unroll
    for (int d = 0; d < AA; ++d) s = fmaf(sv[d], fast_tanh(uj[d] + swa[d]), s);
    if (j == i) s = -10000.f;

    float e = __expf(s);
    if (i >= 1)
        out[1 + (((size_t)(i - 1) * BB + (bi >> 8)) * SS + j)] = e;

    // block-wide sum of e: wave reduce then 4-partial combine
    float r = e;
    #pragma unroll
    for (int off = 32; off > 0; off >>= 1) r += __shfl_xor(r, off, 64);
    __shared__ float part[4];
    if ((j & 63) == 0) part[j >> 6] = r;
    __syncthreads();
    float tot = part[0] + part[1] + part[2] + part[3];

    if (j == heads[bi])
        ce[bi] = (i >= 1) ? (__logf(tot) - s) : 0.f;
}

// -------------------------------------------------------------------------
// Kernel 5: deterministic loss reduction: sum(ce)/B into out[0].
// -------------------------------------------------------------------------
__global__ __launch_bounds__(256) void k_loss(const float* __restrict__ ce,
                                              float* __restrict__ out)
{
    __shared__ float red[256];
    int t = threadIdx.x;
    float a = 0.f;
    for (int k = t; k < BB * SS; k += 256) a += ce[k];
    red[t] = a; __syncthreads();
    for (int off = 128; off > 0; off >>= 1) {
        if (t < off) red[t] += red[t + off];
        __syncthreads();
    }
    if (t == 0) out[0] = red[0] * (1.f / BB);
}

extern "C" void kernel_launch(void* const* d_in, const int* in_sizes, int n_in,
                              void* d_out, int out_size, void* d_ws, size_t ws_size,
                              hipStream_t stream)
{
    const int*   words = (const int*)  d_in[0];
    const int*   pos   = (const int*)  d_in[1];
    const float* morph = (const float*)d_in[2];
    const int*   heads = (const int*)  d_in[3];
    const float* wtab  = (const float*)d_in[4];
    const float* ptab  = (const float*)d_in[5];
    const float* Wxf   = (const float*)d_in[6];
    const float* Whf   = (const float*)d_in[7];
    const float* bf    = (const float*)d_in[8];
    const float* Wxb   = (const float*)d_in[9];
    const float* Whb   = (const float*)d_in[10];
    const float* bb    = (const float*)d_in[11];
    const float* Wu    = (const float*)d_in[12];
    const float* bu    = (const float*)d_in[13];
    const float* Ww    = (const float*)d_in[14];
    const float* bw    = (const float*)d_in[15];
    const float* v     = (const float*)d_in[16];
    float* out = (float*)d_out;

    // workspace layout (floats)
    float* xgf  = (float*)d_ws;                 // 8192*24
    float* xgb  = xgf  + (size_t)BB*SS*G4;      // 8192*24
    float* repr = xgb  + (size_t)BB*SS*G4;      // 8192*12
    float* ua   = repr + (size_t)BB*SS*2*HH;    // 8192*12
    float* wa   = ua   + (size_t)BB*SS*AA;      // 8192*12
    float* ce   = wa   + (size_t)BB*SS*AA;      // 8192

    k_embed_proj<<<(BB * SS) / NP, 256, 0, stream>>>(words, pos, morph, wtab, ptab,
                                                     Wxf, bf, Wxb, bb, xgf, xgb);
    k_lstm<<<BB * 2, 64, 0, stream>>>(xgf, xgb, Whf, Whb, repr);
    k_uawa<<<(BB * SS) / 256, 256, 0, stream>>>(repr, Wu, bu, Ww, bw, ua, wa);
    k_score<<<BB * SS, 256, 0, stream>>>(ua, wa, v, heads, out, ce);
    k_loss<<<1, 256, 0, stream>>>(ce, out);
}

// Round 3
// 122.096 us; speedup vs baseline: 2.3088x; 1.1737x over previous
//
#include <hip/hip_runtime.h>
#include <hip/hip_bf16.h>

// Problem constants
#define BB 32
#define SS 256
#define DD 300
#define PDD 32
#define MM 66
#define FF 398      // D + PD + M
#define HH 6
#define G4 24       // 4*H
#define AA 12

__device__ __forceinline__ float fast_rcp(float x) { return __builtin_amdgcn_rcpf(x); }
__device__ __forceinline__ float sigmoidf_(float x) { return fast_rcp(1.f + __expf(-x)); }
__device__ __forceinline__ float fast_tanh(float x) {
    return 1.f - 2.f * fast_rcp(__expf(2.f * x) + 1.f);
}
__device__ __forceinline__ float bcast_lane(float x, int l) {
    return __int_as_float(__builtin_amdgcn_readlane(__float_as_int(x), l));
}

// -------------------------------------------------------------------------
// Kernel 1 (v2): embed+concat+input projection as an LDS-tiled GEMM.
// Grid: 128 position-groups x 2 directions = 256 blocks, 256 threads.
// Block computes xg[dir][64 pos][24 out]. K tiled in 4 chunks of 100
// (3 word-table tiles + 1 pos/morph/pad tile). Register tile 2 pos x 3 out,
// float4 LDS reads, bank-conflict-free (feat spacing 100 = 4 mod 32,
// W spacing 300 = 12 mod 32).
// -------------------------------------------------------------------------
__global__ __launch_bounds__(256) void k_embed_proj(
    const int* __restrict__ words, const int* __restrict__ pos,
    const float* __restrict__ morph, const float* __restrict__ wtab,
    const float* __restrict__ ptab,
    const float* __restrict__ Wxf, const float* __restrict__ bfv,
    const float* __restrict__ Wxb, const float* __restrict__ bbv,
    float* __restrict__ xgf, float* __restrict__ xgb)
{
    __shared__ float sfeat[64 * 100];   // 25.6 KB
    __shared__ float sW[G4 * 100];      //  9.6 KB

    int t   = threadIdx.x;
    int pg  = blockIdx.x >> 1;
    int dir = blockIdx.x & 1;
    int bs0 = pg * 64;

    const float* Wx   = dir ? Wxb : Wxf;
    const float* bias = dir ? bbv : bfv;
    float*       xg   = dir ? xgb : xgf;

    int tx = t & 7;          // output group: j = 3*tx + {0,1,2}
    int ty = t >> 3;         // position group: p = ty, ty+32

    float a00 = 0.f, a01 = 0.f, a02 = 0.f;   // pos ty
    float a10 = 0.f, a11 = 0.f, a12 = 0.f;   // pos ty+32

    for (int tile = 0; tile < 4; ++tile) {
        // ---- stage feats tile [64][100] ----
        if (tile < 3) {
            // pure word-table range: k in [tile*100, tile*100+100)
            for (int idx = t; idx < 64 * 25; idx += 256) {
                int p = idx / 25, f = idx % 25;
                const float4* src = (const float4*)(wtab +
                    (size_t)words[bs0 + p] * DD + tile * 100);
                ((float4*)sfeat)[p * 25 + f] = src[f];
            }
        } else {
            // k in [300,400): pos(32) + morph(66) + zero pad(2)
            for (int idx = t; idx < 64 * 100; idx += 256) {
                int p = idx / 100, kk = idx % 100;
                float vv;
                if (kk < PDD)           vv = ptab[pos[bs0 + p] * PDD + kk];
                else if (kk < PDD + MM) vv = morph[(size_t)(bs0 + p) * MM + (kk - PDD)];
                else                    vv = 0.f;
                sfeat[p * 100 + kk] = vv;
            }
        }
        // ---- stage W tile [24][100] (transposed; coalesced global read) ----
        for (int idx = t; idx < G4 * 100; idx += 256) {
            int kk = idx / G4, j = idx % G4;
            int k = tile * 100 + kk;
            sW[j * 100 + kk] = (k < FF) ? Wx[k * G4 + j] : 0.f;
        }
        __syncthreads();

        // ---- compute: 25 float4 steps, 5 ds_read_b128 + 24 fma each ----
        const float4* F0 = (const float4*)(sfeat + ty * 100);
        const float4* F1 = (const float4*)(sfeat + (ty + 32) * 100);
        const float4* W0 = (const float4*)(sW + (3 * tx + 0) * 100);
        const float4* W1 = (const float4*)(sW + (3 * tx + 1) * 100);
        const float4* W2 = (const float4*)(sW + (3 * tx + 2) * 100);
        #pragma unroll 5
        for (int q = 0; q < 25; ++q) {
            float4 f0 = F0[q], f1 = F1[q];
            float4 w0 = W0[q], w1 = W1[q], w2 = W2[q];
            a00 = fmaf(f0.x, w0.x, a00); a00 = fmaf(f0.y, w0.y, a00);
            a00 = fmaf(f0.z, w0.z, a00); a00 = fmaf(f0.w, w0.w, a00);
            a01 = fmaf(f0.x, w1.x, a01); a01 = fmaf(f0.y, w1.y, a01);
            a01 = fmaf(f0.z, w1.z, a01); a01 = fmaf(f0.w, w1.w, a01);
            a02 = fmaf(f0.x, w2.x, a02); a02 = fmaf(f0.y, w2.y, a02);
            a02 = fmaf(f0.z, w2.z, a02); a02 = fmaf(f0.w, w2.w, a02);
            a10 = fmaf(f1.x, w0.x, a10); a10 = fmaf(f1.y, w0.y, a10);
            a10 = fmaf(f1.z, w0.z, a10); a10 = fmaf(f1.w, w0.w, a10);
            a11 = fmaf(f1.x, w1.x, a11); a11 = fmaf(f1.y, w1.y, a11);
            a11 = fmaf(f1.z, w1.z, a11); a11 = fmaf(f1.w, w1.w, a11);
            a12 = fmaf(f1.x, w2.x, a12); a12 = fmaf(f1.y, w2.y, a12);
            a12 = fmaf(f1.z, w2.z, a12); a12 = fmaf(f1.w, w2.w, a12);
        }
        __syncthreads();
    }

    int j0 = 3 * tx;
    float b0 = bias[j0], b1 = bias[j0 + 1], b2 = bias[j0 + 2];
    float* o0 = xg + (size_t)(bs0 + ty) * G4 + j0;
    float* o1 = xg + (size_t)(bs0 + ty + 32) * G4 + j0;
    o0[0] = a00 + b0; o0[1] = a01 + b1; o0[2] = a02 + b2;
    o1[0] = a10 + b0; o1[1] = a11 + b1; o1[2] = a12 + b2;
}

// -------------------------------------------------------------------------
// Kernel 2: LSTM recurrence, shuffle-free critical path (readlane bcast).
// -------------------------------------------------------------------------
__global__ __launch_bounds__(64) void k_lstm(
    const float* __restrict__ xgf, const float* __restrict__ xgb,
    const float* __restrict__ Whf, const float* __restrict__ Whb,
    float* __restrict__ repr)
{
    __shared__ float sxg[SS * G4];          // 24576 B
    int blk = blockIdx.x;                   // 0..63
    int dir = blk >> 5;                     // 0 = fwd, 1 = bwd
    int b   = blk & 31;
    int lane = threadIdx.x;

    const float* xg = (dir ? xgb : xgf) + (size_t)b * SS * G4;
    const float* Wh = dir ? Whb : Whf;

    {
        const float4* src = (const float4*)xg;
        float4* dst = (float4*)sxg;
        for (int u = 0; u < (SS * G4 / 4) / 64; ++u)
            dst[lane + u * 64] = src[lane + u * 64];
    }

    int k = lane % HH;
    float wh0[HH], wh1[HH], wh2[HH], wh3[HH];
    #pragma unroll
    for (int m = 0; m < HH; ++m) {
        wh0[m] = Wh[m * G4 + 0 * HH + k];
        wh1[m] = Wh[m * G4 + 1 * HH + k];
        wh2[m] = Wh[m * G4 + 2 * HH + k];
        wh3[m] = Wh[m * G4 + 3 * HH + k];
    }
    float sh[HH];
    #pragma unroll
    for (int m = 0; m < HH; ++m) sh[m] = 0.f;
    float c = 0.f;
    __syncthreads();

    float* outp = repr + (size_t)b * SS * (2 * HH) + dir * HH + k;

    int s = dir ? (SS - 1) : 0;
    const float* xr = sxg + s * G4 + k;
    float gi = xr[0], gf = xr[HH], gc = xr[2 * HH], go = xr[3 * HH];

    for (int t = 0; t < SS; ++t) {
        int tn = (t + 1 < SS) ? t + 1 : t;
        int sn = dir ? (SS - 1 - tn) : tn;
        const float* xn = sxg + sn * G4 + k;
        float ni = xn[0], nf = xn[HH], nc = xn[2 * HH], no = xn[3 * HH];

        #pragma unroll
        for (int m = 0; m < HH; ++m) {
            gi = fmaf(sh[m], wh0[m], gi);
            gf = fmaf(sh[m], wh1[m], gf);
            gc = fmaf(sh[m], wh2[m], gc);
            go = fmaf(sh[m], wh3[m], go);
        }
        c = sigmoidf_(gf) * c + sigmoidf_(gi) * fast_tanh(gc);
        float h = sigmoidf_(go) * fast_tanh(c);
        if (lane < HH) outp[(size_t)s * (2 * HH)] = h;
        #pragma unroll
        for (int m = 0; m < HH; ++m) sh[m] = bcast_lane(h, m);

        gi = ni; gf = nf; gc = nc; go = no;
        s = sn;
    }
}

// -------------------------------------------------------------------------
// Kernel 3: ua = repr@Wu+bu ; wa = repr@Ww+bw. One thread per (b,s).
// -------------------------------------------------------------------------
__global__ __launch_bounds__(256) void k_uawa(
    const float* __restrict__ repr,
    const float* __restrict__ Wu, const float* __restrict__ bu,
    const float* __restrict__ Ww, const float* __restrict__ bw,
    float* __restrict__ ua, float* __restrict__ wa)
{
    int bs = blockIdx.x * blockDim.x + threadIdx.x;   // 0..8191
    float r[AA];
    #pragma unroll
    for (int e = 0; e < AA; ++e) r[e] = repr[(size_t)bs * AA + e];
    #pragma unroll
    for (int d = 0; d < AA; ++d) {
        float au = bu[d], aw = bw[d];
        #pragma unroll
        for (int e = 0; e < AA; ++e) {
            au = fmaf(r[e], Wu[e * AA + d], au);
            aw = fmaf(r[e], Ww[e * AA + d], aw);
        }
        ua[(size_t)bs * AA + d] = au;
        wa[(size_t)bs * AA + d] = aw;
    }
}

// -------------------------------------------------------------------------
// Kernel 4: arc scores + sum-exp + CE partials + exp table.
// -------------------------------------------------------------------------
__global__ __launch_bounds__(256) void k_score(
    const float* __restrict__ ua, const float* __restrict__ wa,
    const float* __restrict__ v, const int* __restrict__ heads,
    float* __restrict__ out, float* __restrict__ ce)
{
    int bi = blockIdx.x;            // b*S + i
    int i  = bi & 255;
    int j  = threadIdx.x;

    __shared__ float swa[AA], sv[AA];
    if (j < AA) { swa[j] = wa[(size_t)bi * AA + j]; sv[j] = v[j]; }
    __syncthreads();

    const float* uj = ua + ((size_t)(bi & ~255) + j) * AA;
    float s = 0.f;
    #pragma unroll
    for (int d = 0; d < AA; ++d) s = fmaf(sv[d], fast_tanh(uj[d] + swa[d]), s);
    if (j == i) s = -10000.f;

    float e = __expf(s);
    if (i >= 1)
        out[1 + (((size_t)(i - 1) * BB + (bi >> 8)) * SS + j)] = e;

    float r = e;
    #pragma unroll
    for (int off = 32; off > 0; off >>= 1) r += __shfl_xor(r, off, 64);
    __shared__ float part[4];
    if ((j & 63) == 0) part[j >> 6] = r;
    __syncthreads();
    float tot = part[0] + part[1] + part[2] + part[3];

    if (j == heads[bi])
        ce[bi] = (i >= 1) ? (__logf(tot) - s) : 0.f;
}

// -------------------------------------------------------------------------
// Kernel 5: deterministic loss reduction: sum(ce)/B into out[0].
// -------------------------------------------------------------------------
__global__ __launch_bounds__(256) void k_loss(const float* __restrict__ ce,
                                              float* __restrict__ out)
{
    __shared__ float red[256];
    int t = threadIdx.x;
    float a = 0.f;
    for (int k = t; k < BB * SS; k += 256) a += ce[k];
    red[t] = a; __syncthreads();
    for (int off = 128; off > 0; off >>= 1) {
        if (t < off) red[t] += red[t + off];
        __syncthreads();
    }
    if (t == 0) out[0] = red[0] * (1.f / BB);
}

extern "C" void kernel_launch(void* const* d_in, const int* in_sizes, int n_in,
                              void* d_out, int out_size, void* d_ws, size_t ws_size,
                              hipStream_t stream)
{
    const int*   words = (const int*)  d_in[0];
    const int*   pos   = (const int*)  d_in[1];
    const float* morph = (const float*)d_in[2];
    const int*   heads = (const int*)  d_in[3];
    const float* wtab  = (const float*)d_in[4];
    const float* ptab  = (const float*)d_in[5];
    const float* Wxf   = (const float*)d_in[6];
    const float* Whf   = (const float*)d_in[7];
    const float* bf    = (const float*)d_in[8];
    const float* Wxb   = (const float*)d_in[9];
    const float* Whb   = (const float*)d_in[10];
    const float* bb    = (const float*)d_in[11];
    const float* Wu    = (const float*)d_in[12];
    const float* bu    = (const float*)d_in[13];
    const float* Ww    = (const float*)d_in[14];
    const float* bw    = (const float*)d_in[15];
    const float* v     = (const float*)d_in[16];
    float* out = (float*)d_out;

    // workspace layout (floats)
    float* xgf  = (float*)d_ws;                 // 8192*24
    float* xgb  = xgf  + (size_t)BB*SS*G4;      // 8192*24
    float* repr = xgb  + (size_t)BB*SS*G4;      // 8192*12
    float* ua   = repr + (size_t)BB*SS*2*HH;    // 8192*12
    float* wa   = ua   + (size_t)BB*SS*AA;      // 8192*12
    float* ce   = wa   + (size_t)BB*SS*AA;      // 8192

    k_embed_proj<<<256, 256, 0, stream>>>(words, pos, morph, wtab, ptab,
                                          Wxf, bf, Wxb, bb, xgf, xgb);
    k_lstm<<<BB * 2, 64, 0, stream>>>(xgf, xgb, Whf, Whb, repr);
    k_uawa<<<(BB * SS) / 256, 256, 0, stream>>>(repr, Wu, bu, Ww, bw, ua, wa);
    k_score<<<BB * SS, 256, 0, stream>>>(ua, wa, v, heads, out, ce);
    k_loss<<<1, 256, 0, stream>>>(ce, out);
}

// Round 4
// 95.412 us; speedup vs baseline: 2.9546x; 1.2797x over previous
//
#include <hip/hip_runtime.h>
#include <hip/hip_bf16.h>

// Problem constants
#define BB 32
#define SS 256
#define DD 300
#define PDD 32
#define MM 66
#define FF 398      // D + PD + M
#define HH 6
#define G4 24       // 4*H
#define AA 12

__device__ __forceinline__ float fast_rcp(float x) { return __builtin_amdgcn_rcpf(x); }
__device__ __forceinline__ float sigmoidf_(float x) { return fast_rcp(1.f + __expf(-x)); }
__device__ __forceinline__ float fast_tanh(float x) {
    return 1.f - 2.f * fast_rcp(__expf(2.f * x) + 1.f);
}
__device__ __forceinline__ float bcast_lane(float x, int l) {
    return __int_as_float(__builtin_amdgcn_readlane(__float_as_int(x), l));
}

// -------------------------------------------------------------------------
// Kernel 1 (v3): embed+concat+input projection, both directions fused.
// 16 positions/block -> grid 512 (2 blocks/CU, 8 waves/CU). Feats gathered
// once for both dirs. Register tile: 1 pos x 3 cols (48 cols = fwd24|bwd24).
// K tiled 4 x 100. W rows stride 100 (=4 mod 32): 16 col-groups hit 8 bank
// starts -> 2-way conflict = free; F reads broadcast within 16 lanes.
// -------------------------------------------------------------------------
#define EP_POS 16
__global__ __launch_bounds__(256) void k_embed_proj(
    const int* __restrict__ words, const int* __restrict__ pos,
    const float* __restrict__ morph, const float* __restrict__ wtab,
    const float* __restrict__ ptab,
    const float* __restrict__ Wxf, const float* __restrict__ bfv,
    const float* __restrict__ Wxb, const float* __restrict__ bbv,
    float* __restrict__ xgf, float* __restrict__ xgb)
{
    __shared__ float sfeat[EP_POS * 100];   //  6.4 KB
    __shared__ float sW[48 * 100];          // 19.2 KB

    int t   = threadIdx.x;
    int bs0 = blockIdx.x * EP_POS;

    int cg = t & 15;         // col group: cols 3*cg .. 3*cg+2 (0..47)
    int p  = t >> 4;         // position 0..15
    float a0 = 0.f, a1 = 0.f, a2 = 0.f;

    for (int tile = 0; tile < 4; ++tile) {
        // ---- stage feats tile [16][100] ----
        if (tile < 3) {
            for (int idx = t; idx < EP_POS * 25; idx += 256) {
                int pp = idx / 25, f = idx % 25;
                const float4* srcr = (const float4*)(wtab +
                    (size_t)words[bs0 + pp] * DD + tile * 100);
                ((float4*)sfeat)[pp * 25 + f] = srcr[f];
            }
        } else {
            for (int idx = t; idx < EP_POS * 100; idx += 256) {
                int pp = idx / 100, kk = idx % 100;
                float vv;
                if (kk < PDD)           vv = ptab[pos[bs0 + pp] * PDD + kk];
                else if (kk < PDD + MM) vv = morph[(size_t)(bs0 + pp) * MM + (kk - PDD)];
                else                    vv = 0.f;
                sfeat[pp * 100 + kk] = vv;
            }
        }
        // ---- stage W tile [48][100]: cols 0-23 fwd, 24-47 bwd ----
        for (int idx = t; idx < 2400; idx += 256) {
            int kk = idx / 24, j = idx % 24;
            int k = tile * 100 + kk;
            float wf = (k < FF) ? Wxf[k * G4 + j] : 0.f;
            float wb = (k < FF) ? Wxb[k * G4 + j] : 0.f;
            sW[j * 100 + kk]        = wf;
            sW[(24 + j) * 100 + kk] = wb;
        }
        __syncthreads();

        // ---- compute: 25 float4 steps, 4 ds_read_b128 + 12 fma each ----
        const float4* Fp = (const float4*)(sfeat + p * 100);
        const float4* W0 = (const float4*)(sW + (3 * cg + 0) * 100);
        const float4* W1 = (const float4*)(sW + (3 * cg + 1) * 100);
        const float4* W2 = (const float4*)(sW + (3 * cg + 2) * 100);
        #pragma unroll 5
        for (int q = 0; q < 25; ++q) {
            float4 f0 = Fp[q];
            float4 w0 = W0[q], w1 = W1[q], w2 = W2[q];
            a0 = fmaf(f0.x, w0.x, a0); a0 = fmaf(f0.y, w0.y, a0);
            a0 = fmaf(f0.z, w0.z, a0); a0 = fmaf(f0.w, w0.w, a0);
            a1 = fmaf(f0.x, w1.x, a1); a1 = fmaf(f0.y, w1.y, a1);
            a1 = fmaf(f0.z, w1.z, a1); a1 = fmaf(f0.w, w1.w, a1);
            a2 = fmaf(f0.x, w2.x, a2); a2 = fmaf(f0.y, w2.y, a2);
            a2 = fmaf(f0.z, w2.z, a2); a2 = fmaf(f0.w, w2.w, a2);
        }
        __syncthreads();
    }

    int c0  = 3 * cg;                 // never straddles the 24 boundary
    int dir = c0 >= 24 ? 1 : 0;
    int jj  = c0 - dir * 24;
    const float* bias = dir ? bbv : bfv;
    float*       xg   = dir ? xgb : xgf;
    float* o = xg + (size_t)(bs0 + p) * G4 + jj;
    o[0] = a0 + bias[jj]; o[1] = a1 + bias[jj + 1]; o[2] = a2 + bias[jj + 2];
}

// -------------------------------------------------------------------------
// Kernel 2 (v3): LSTM recurrence. One wave per (batch, direction).
// xg staged into LDS PRE-REVERSED for bwd so the time loop is dir-free with
// compile-time offsets (unrolled x2, ds_read2-mergeable). h written to an
// LDS ring (no global stores in the loop), bulk-copied at the end.
// -------------------------------------------------------------------------
__global__ __launch_bounds__(64) void k_lstm(
    const float* __restrict__ xgf, const float* __restrict__ xgb,
    const float* __restrict__ Whf, const float* __restrict__ Whb,
    float* __restrict__ repr)
{
    __shared__ float sxg[SS * G4];          // 24576 B
    __shared__ float hbuf[SS * HH];         //  6144 B
    int blk = blockIdx.x;                   // 0..63
    int dir = blk >> 5;
    int b   = blk & 31;
    int lane = threadIdx.x;

    const float* xg = (dir ? xgb : xgf) + (size_t)b * SS * G4;
    const float* Wh = dir ? Whb : Whf;

    // stage xg -> LDS, rows reversed for bwd
    {
        const float4* src = (const float4*)xg;
        float4* dst = (float4*)sxg;
        for (int u = 0; u < 24; ++u) {
            int d = lane + u * 64;          // float4 index 0..1535
            int row = d / 6, col = d - row * 6;
            int drow = dir ? (SS - 1 - row) : row;
            dst[drow * 6 + col] = src[d];
        }
    }

    int k = lane % HH;                      // cell id (lanes >=6 duplicate)
    float wh0[HH], wh1[HH], wh2[HH], wh3[HH];
    #pragma unroll
    for (int m = 0; m < HH; ++m) {
        wh0[m] = Wh[m * G4 + 0 * HH + k];
        wh1[m] = Wh[m * G4 + 1 * HH + k];
        wh2[m] = Wh[m * G4 + 2 * HH + k];
        wh3[m] = Wh[m * G4 + 3 * HH + k];
    }
    float sh[HH];
    #pragma unroll
    for (int m = 0; m < HH; ++m) sh[m] = 0.f;
    float c = 0.f;
    bool wr = lane < HH;
    __syncthreads();

    const float* xb = sxg + k;

    for (int t = 0; t < SS; t += 2) {
        // ---- step A ----
        float gi = xb[t * 24 + 0],  gf = xb[t * 24 + 6];
        float gc = xb[t * 24 + 12], go = xb[t * 24 + 18];
        // step B inputs (independent -> overlap with A's chain)
        float ni = xb[t * 24 + 24], nf = xb[t * 24 + 30];
        float nc = xb[t * 24 + 36], no = xb[t * 24 + 42];

        #pragma unroll
        for (int m = 0; m < HH; ++m) {
            gf = fmaf(sh[m], wh1[m], gf);
            gc = fmaf(sh[m], wh2[m], gc);
            gi = fmaf(sh[m], wh0[m], gi);
            go = fmaf(sh[m], wh3[m], go);
        }
        c = sigmoidf_(gf) * c + sigmoidf_(gi) * fast_tanh(gc);
        float h = sigmoidf_(go) * fast_tanh(c);
        if (wr) hbuf[t * HH + k] = h;
        #pragma unroll
        for (int m = 0; m < HH; ++m) sh[m] = bcast_lane(h, m);

        // ---- step B ----
        #pragma unroll
        for (int m = 0; m < HH; ++m) {
            nf = fmaf(sh[m], wh1[m], nf);
            nc = fmaf(sh[m], wh2[m], nc);
            ni = fmaf(sh[m], wh0[m], ni);
            no = fmaf(sh[m], wh3[m], no);
        }
        c = sigmoidf_(nf) * c + sigmoidf_(ni) * fast_tanh(nc);
        float h2 = sigmoidf_(no) * fast_tanh(c);
        if (wr) hbuf[(t + 1) * HH + k] = h2;
        #pragma unroll
        for (int m = 0; m < HH; ++m) sh[m] = bcast_lane(h2, m);
    }
    __syncthreads();

    // bulk copy hbuf -> repr (undo reversal for bwd)
    for (int u = 0; u < (SS * HH) / 64; ++u) {
        int idx = lane + u * 64;
        int tt = idx / 6, cc = idx - tt * 6;
        int s = dir ? (SS - 1 - tt) : tt;
        repr[((size_t)b * SS + s) * (2 * HH) + dir * HH + cc] = hbuf[idx];
    }
}

// -------------------------------------------------------------------------
// Kernel 3: ua = repr@Wu+bu ; wa = repr@Ww+bw. One thread per (b,s).
// -------------------------------------------------------------------------
__global__ __launch_bounds__(256) void k_uawa(
    const float* __restrict__ repr,
    const float* __restrict__ Wu, const float* __restrict__ bu,
    const float* __restrict__ Ww, const float* __restrict__ bw,
    float* __restrict__ ua, float* __restrict__ wa)
{
    int bs = blockIdx.x * blockDim.x + threadIdx.x;   // 0..8191
    float r[AA];
    #pragma unroll
    for (int e = 0; e < AA; ++e) r[e] = repr[(size_t)bs * AA + e];
    #pragma unroll
    for (int d = 0; d < AA; ++d) {
        float au = bu[d], aw = bw[d];
        #pragma unroll
        for (int e = 0; e < AA; ++e) {
            au = fmaf(r[e], Wu[e * AA + d], au);
            aw = fmaf(r[e], Ww[e * AA + d], aw);
        }
        ua[(size_t)bs * AA + d] = au;
        wa[(size_t)bs * AA + d] = aw;
    }
}

// -------------------------------------------------------------------------
// Kernel 4: arc scores + sum-exp + CE partials + exp table.
// -------------------------------------------------------------------------
__global__ __launch_bounds__(256) void k_score(
    const float* __restrict__ ua, const float* __restrict__ wa,
    const float* __restrict__ v, const int* __restrict__ heads,
    float* __restrict__ out, float* __restrict__ ce)
{
    int bi = blockIdx.x;            // b*S + i
    int i  = bi & 255;
    int j  = threadIdx.x;

    __shared__ float swa[AA], sv[AA];
    if (j < AA) { swa[j] = wa[(size_t)bi * AA + j]; sv[j] = v[j]; }
    __syncthreads();

    const float* uj = ua + ((size_t)(bi & ~255) + j) * AA;
    float s = 0.f;
    #pragma unroll
    for (int d = 0; d < AA; ++d) s = fmaf(sv[d], fast_tanh(uj[d] + swa[d]), s);
    if (j == i) s = -10000.f;

    float e = __expf(s);
    if (i >= 1)
        out[1 + (((size_t)(i - 1) * BB + (bi >> 8)) * SS + j)] = e;

    float r = e;
    #pragma unroll
    for (int off = 32; off > 0; off >>= 1) r += __shfl_xor(r, off, 64);
    __shared__ float part[4];
    if ((j & 63) == 0) part[j >> 6] = r;
    __syncthreads();
    float tot = part[0] + part[1] + part[2] + part[3];

    if (j == heads[bi])
        ce[bi] = (i >= 1) ? (__logf(tot) - s) : 0.f;
}

// -------------------------------------------------------------------------
// Kernel 5: deterministic loss reduction: sum(ce)/B into out[0].
// -------------------------------------------------------------------------
__global__ __launch_bounds__(256) void k_loss(const float* __restrict__ ce,
                                              float* __restrict__ out)
{
    __shared__ float red[256];
    int t = threadIdx.x;
    float a = 0.f;
    for (int k = t; k < BB * SS; k += 256) a += ce[k];
    red[t] = a; __syncthreads();
    for (int off = 128; off > 0; off >>= 1) {
        if (t < off) red[t] += red[t + off];
        __syncthreads();
    }
    if (t == 0) out[0] = red[0] * (1.f / BB);
}

extern "C" void kernel_launch(void* const* d_in, const int* in_sizes, int n_in,
                              void* d_out, int out_size, void* d_ws, size_t ws_size,
                              hipStream_t stream)
{
    const int*   words = (const int*)  d_in[0];
    const int*   pos   = (const int*)  d_in[1];
    const float* morph = (const float*)d_in[2];
    const int*   heads = (const int*)  d_in[3];
    const float* wtab  = (const float*)d_in[4];
    const float* ptab  = (const float*)d_in[5];
    const float* Wxf   = (const float*)d_in[6];
    const float* Whf   = (const float*)d_in[7];
    const float* bf    = (const float*)d_in[8];
    const float* Wxb   = (const float*)d_in[9];
    const float* Whb   = (const float*)d_in[10];
    const float* bb    = (const float*)d_in[11];
    const float* Wu    = (const float*)d_in[12];
    const float* bu    = (const float*)d_in[13];
    const float* Ww    = (const float*)d_in[14];
    const float* bw    = (const float*)d_in[15];
    const float* v     = (const float*)d_in[16];
    float* out = (float*)d_out;

    // workspace layout (floats)
    float* xgf  = (float*)d_ws;                 // 8192*24
    float* xgb  = xgf  + (size_t)BB*SS*G4;      // 8192*24
    float* repr = xgb  + (size_t)BB*SS*G4;      // 8192*12
    float* ua   = repr + (size_t)BB*SS*2*HH;    // 8192*12
    float* wa   = ua   + (size_t)BB*SS*AA;      // 8192*12
    float* ce   = wa   + (size_t)BB*SS*AA;      // 8192

    k_embed_proj<<<(BB * SS) / EP_POS, 256, 0, stream>>>(words, pos, morph, wtab, ptab,
                                                         Wxf, bf, Wxb, bb, xgf, xgb);
    k_lstm<<<BB * 2, 64, 0, stream>>>(xgf, xgb, Whf, Whb, repr);
    k_uawa<<<(BB * SS) / 256, 256, 0, stream>>>(repr, Wu, bu, Ww, bw, ua, wa);
    k_score<<<BB * SS, 256, 0, stream>>>(ua, wa, v, heads, out, ce);
    k_loss<<<1, 256, 0, stream>>>(ce, out);
}